// Round 1
// baseline (823.129 us; speedup 1.0000x reference)
//
#include <hip/hip_runtime.h>

#define BB 16
#define CC 256
#define HW 9216   // 96*96

// ---------------- K1: adaptive avg pool 96x96 -> 8x8 per (b,c) plane ----------------
__global__ __launch_bounds__(256) void k_pool(const float* __restrict__ x,
                                              float* __restrict__ pooled) {
  int bc = blockIdx.x;                    // b*256 + c
  const float* plane = x + (size_t)bc * HW;
  __shared__ float rowwin[96][8];
  for (int idx = threadIdx.x; idx < 96 * 8; idx += 256) {
    int y = idx >> 3, wx = idx & 7;
    const float* r = plane + y * 96 + wx * 12;
    float s = 0.f;
#pragma unroll
    for (int i = 0; i < 12; ++i) s += r[i];
    rowwin[y][wx] = s;
  }
  __syncthreads();
  if (threadIdx.x < 64) {
    int wy = threadIdx.x >> 3, wx = threadIdx.x & 7;
    float s = 0.f;
#pragma unroll
    for (int i = 0; i < 12; ++i) s += rowwin[wy * 12 + i][wx];
    pooled[(size_t)bc * 64 + threadIdx.x] = s * (1.0f / 144.0f);  // p = wy*8+wx
  }
}

// ---------------- K2: inverse L2 norm over channels of pooled, per (b,p) ----------------
__global__ void k_invn(const float* __restrict__ pooled, float* __restrict__ invn) {
  int b = blockIdx.x;
  int p = threadIdx.x;                    // 64 threads
  const float* pb = pooled + (size_t)b * CC * 64;
  float s = 0.f;
  for (int c = 0; c < CC; ++c) { float v = pb[c * 64 + p]; s += v * v; }
  invn[b * 64 + p] = 1.0f / fmaxf(sqrtf(s), 1e-12f);
}

// ---------------- K3: M[b][c][o] = sum_p W1[o][p] * ker[b][c][p] ----------------
__global__ __launch_bounds__(256) void k_M(const float* __restrict__ pooled,
                                           const float* __restrict__ invn,
                                           const float* __restrict__ W1,
                                           float* __restrict__ M) {
  int b = blockIdx.x;
  __shared__ float kers[64][256];         // [p][c], 64KB
  const float* pb = pooled + (size_t)b * CC * 64;
  for (int i = threadIdx.x; i < CC * 64; i += 256) {
    int c = i >> 6, p = i & 63;
    kers[p][c] = pb[i] * invn[b * 64 + p];
  }
  __syncthreads();
  int c = threadIdx.x;                    // 0..255
  float* Mb = M + (size_t)b * CC * 64;
  for (int o = 0; o < 64; ++o) {
    float s = 0.f;
#pragma unroll 16
    for (int p = 0; p < 64; ++p) s += W1[o * 64 + p] * kers[p][c];
    Mb[c * 64 + o] = s;
  }
}

// ---------------- K4: W3 transpose: W3T[c][o] = W3[o][c], c<320 ----------------
__global__ void k_w3t(const float* __restrict__ W3, float* __restrict__ W3T) {
  int i = blockIdx.x * 256 + threadIdx.x;
  if (i < 320 * 64) {
    int c = i >> 6, o = i & 63;
    W3T[i] = W3[o * 320 + c];
  }
}

// ---------------- K5: h_pre[b][o][pix] = invnorm(pix)*(M[b]·x[b,:,pix]) + b1[o] ----------------
__global__ __launch_bounds__(256) void k_gemm1(const float* __restrict__ x,
                                               const float* __restrict__ M,
                                               const float* __restrict__ b1,
                                               float* __restrict__ hpre) {
  int tile = blockIdx.x, b = blockIdx.y, t = threadIdx.x;
  int pixbase = tile * 256;
  __shared__ float xs[16][256];
  __shared__ float Ms[16][64];
  __shared__ float ssqs[256];
  const float* xb = x + (size_t)b * CC * HW + pixbase;
  const float* Mb = M + (size_t)b * CC * 64;
  float acc[8][8];
#pragma unroll
  for (int i = 0; i < 8; ++i)
#pragma unroll
    for (int j = 0; j < 8; ++j) acc[i][j] = 0.f;
  float sq = 0.f;
  int to = t >> 5, tp = t & 31;
  for (int c0 = 0; c0 < CC; c0 += 16) {
#pragma unroll
    for (int i = 0; i < 16; ++i) {
      float v = xb[(size_t)(c0 + i) * HW + t];
      xs[i][t] = v;
      sq += v * v;                        // per-pixel sum of squares (pixel t)
    }
    for (int i = t; i < 16 * 64; i += 256)
      Ms[i >> 6][i & 63] = Mb[(size_t)(c0 + (i >> 6)) * 64 + (i & 63)];
    __syncthreads();
#pragma unroll
    for (int ci = 0; ci < 16; ++ci) {
      float a[8], xv[8];
#pragma unroll
      for (int i = 0; i < 8; ++i) a[i] = Ms[ci][to * 8 + i];
#pragma unroll
      for (int j = 0; j < 8; ++j) xv[j] = xs[ci][tp + 32 * j];
#pragma unroll
      for (int i = 0; i < 8; ++i)
#pragma unroll
        for (int j = 0; j < 8; ++j) acc[i][j] = fmaf(a[i], xv[j], acc[i][j]);
    }
    __syncthreads();
  }
  ssqs[t] = sq;
  __syncthreads();
  float inv[8];
#pragma unroll
  for (int j = 0; j < 8; ++j)
    inv[j] = 1.0f / fmaxf(sqrtf(ssqs[tp + 32 * j]), 1e-12f);
#pragma unroll
  for (int i = 0; i < 8; ++i) {
    int o = to * 8 + i;
    float bias = b1[o];
    float* dst = hpre + ((size_t)b * 64 + o) * HW + pixbase;
#pragma unroll
    for (int j = 0; j < 8; ++j) dst[tp + 32 * j] = fmaf(acc[i][j], inv[j], bias);
  }
}

// ---------------- K6: instance-norm stats per (b,o): scale=rstd, shift=-mean*rstd ----------------
__global__ __launch_bounds__(256) void k_stats(const float* __restrict__ src,
                                               float* __restrict__ scale,
                                               float* __restrict__ shift,
                                               float eps) {
  int bo = blockIdx.x;
  const float* p = src + (size_t)bo * HW;
  float s = 0.f, ss = 0.f;
  for (int i = threadIdx.x; i < HW; i += 256) {
    float v = p[i];
    s += v;
    ss += v * v;
  }
  __shared__ float sh[8];
  int lane = threadIdx.x & 63, w = threadIdx.x >> 6;
#pragma unroll
  for (int off = 32; off; off >>= 1) {
    s += __shfl_down(s, off);
    ss += __shfl_down(ss, off);
  }
  if (lane == 0) { sh[w] = s; sh[4 + w] = ss; }
  __syncthreads();
  if (threadIdx.x == 0) {
    float S = sh[0] + sh[1] + sh[2] + sh[3];
    float SS = sh[4] + sh[5] + sh[6] + sh[7];
    float mean = S * (1.0f / (float)HW);
    float var = SS * (1.0f / (float)HW) - mean * mean;
    float rstd = rsqrtf(var + eps);
    scale[bo] = rstd;
    shift[bo] = -mean * rstd;
  }
}

// ---------------- K7: conv3x3 over relu(IN(h_pre)), +b2 -> hh (stored in d_out) ----------------
__global__ __launch_bounds__(256) void k_conv(const float* __restrict__ hpre,
                                              const float* __restrict__ scale1,
                                              const float* __restrict__ shift1,
                                              const float* __restrict__ W2,
                                              const float* __restrict__ b2,
                                              float* __restrict__ hh) {
  int og = blockIdx.x & 7;                // output-channel group (8 o2 each)
  int band = blockIdx.x >> 3;             // 12 bands of 8 rows
  int b = blockIdx.y;
  int t = threadIdx.x;
  int r0 = band * 8;
  __shared__ float hs[8][10][97];         // 8 f x (8+2 halo rows) x 96 (+1 pad)
  __shared__ float W2s[8][8][9];
  __shared__ float scs[64], shs[64];
  if (t < 64) { scs[t] = scale1[b * 64 + t]; shs[t] = shift1[b * 64 + t]; }
  __syncthreads();
  int po = t >> 6;                        // 0..3 -> pair of o2
  int tp = t & 63;
  int xl = tp & 15;                       // 16 strips of 6 cols
  int yg = tp >> 4;                       // 4 groups of 2 rows
  int xs0 = xl * 6;
  float acc[2][2][6];
#pragma unroll
  for (int a = 0; a < 2; ++a)
#pragma unroll
    for (int c = 0; c < 2; ++c)
#pragma unroll
      for (int d = 0; d < 6; ++d) acc[a][c][d] = 0.f;

  for (int f0 = 0; f0 < 64; f0 += 8) {
    for (int i = t; i < 8 * 10 * 96; i += 256) {
      int f = i / 960, rem = i % 960;
      int y = rem / 96, xx = rem % 96;
      int gy = r0 - 1 + y;
      float v = 0.f;
      if (gy >= 0 && gy < 96) {
        float raw = hpre[((size_t)b * 64 + f0 + f) * HW + gy * 96 + xx];
        v = fmaxf(0.f, fmaf(raw, scs[f0 + f], shs[f0 + f]));
      }
      hs[f][y][xx] = v;
    }
    for (int i = t; i < 8 * 8 * 9; i += 256) {
      int o = i / 72, rem = i % 72;
      int f = rem / 9, tap = rem % 9;
      W2s[o][f][tap] = W2[((size_t)(og * 8 + o) * 64 + f0 + f) * 9 + tap];
    }
    __syncthreads();
#pragma unroll
    for (int f = 0; f < 8; ++f) {
      float rowv[4][8];
#pragma unroll
      for (int rr = 0; rr < 4; ++rr) {
        int ly = yg * 2 + rr;
#pragma unroll
        for (int k = 0; k < 8; ++k) {
          int xx = xs0 - 1 + k;
          int xc = xx < 0 ? 0 : (xx > 95 ? 95 : xx);
          float v = hs[f][ly][xc];
          rowv[rr][k] = (xx >= 0 && xx < 96) ? v : 0.f;
        }
      }
#pragma unroll
      for (int ko = 0; ko < 2; ++ko) {
        int o = po * 2 + ko;
#pragma unroll
        for (int dy = 0; dy < 3; ++dy) {
          float w0 = W2s[o][f][dy * 3 + 0];
          float w1 = W2s[o][f][dy * 3 + 1];
          float w2 = W2s[o][f][dy * 3 + 2];
#pragma unroll
          for (int yy = 0; yy < 2; ++yy) {
            float* R = rowv[yy + dy];
#pragma unroll
            for (int xi = 0; xi < 6; ++xi)
              acc[ko][yy][xi] = fmaf(w0, R[xi],
                                fmaf(w1, R[xi + 1],
                                fmaf(w2, R[xi + 2], acc[ko][yy][xi])));
          }
        }
      }
    }
    __syncthreads();
  }
#pragma unroll
  for (int ko = 0; ko < 2; ++ko) {
    int o2 = og * 8 + po * 2 + ko;
    float bias = b2[o2];
#pragma unroll
    for (int yy = 0; yy < 2; ++yy) {
      int gy = r0 + yg * 2 + yy;
      float* dst = hh + ((size_t)b * 64 + o2) * HW + gy * 96 + xs0;
#pragma unroll
      for (int xi = 0; xi < 6; ++xi) dst[xi] = acc[ko][yy][xi] + bias;
    }
  }
}

// ---------------- K8: out_pre = W3a·x + W3b·hh + b3  (hh and outp both = d_out) ----------------
__global__ __launch_bounds__(256) void k_gemm2(const float* __restrict__ x,
                                               const float* hh,
                                               const float* __restrict__ W3T,
                                               const float* __restrict__ b3,
                                               float* outp) {
  int tile = blockIdx.x, b = blockIdx.y, t = threadIdx.x;
  int pixbase = tile * 256;
  __shared__ float xs[16][256];
  __shared__ float Ws[16][64];
  const float* xb = x + (size_t)b * CC * HW + pixbase;
  const float* hb = hh + (size_t)b * 64 * HW + pixbase;
  float acc[8][8];
#pragma unroll
  for (int i = 0; i < 8; ++i)
#pragma unroll
    for (int j = 0; j < 8; ++j) acc[i][j] = 0.f;
  int to = t >> 5, tp = t & 31;
  for (int k0 = 0; k0 < 320; k0 += 16) {
    const float* src = (k0 < 256) ? (xb + (size_t)k0 * HW) : (hb + (size_t)(k0 - 256) * HW);
#pragma unroll
    for (int i = 0; i < 16; ++i) xs[i][t] = src[(size_t)i * HW + t];
    for (int i = t; i < 16 * 64; i += 256)
      Ws[i >> 6][i & 63] = W3T[(size_t)(k0 + (i >> 6)) * 64 + (i & 63)];
    __syncthreads();
#pragma unroll
    for (int ci = 0; ci < 16; ++ci) {
      float a[8], xv[8];
#pragma unroll
      for (int i = 0; i < 8; ++i) a[i] = Ws[ci][to * 8 + i];
#pragma unroll
      for (int j = 0; j < 8; ++j) xv[j] = xs[ci][tp + 32 * j];
#pragma unroll
      for (int i = 0; i < 8; ++i)
#pragma unroll
        for (int j = 0; j < 8; ++j) acc[i][j] = fmaf(a[i], xv[j], acc[i][j]);
    }
    __syncthreads();
  }
#pragma unroll
  for (int i = 0; i < 8; ++i) {
    int o = to * 8 + i;
    float bias = b3[o];
    float* dst = outp + ((size_t)b * 64 + o) * HW + pixbase;
#pragma unroll
    for (int j = 0; j < 8; ++j) dst[tp + 32 * j] = acc[i][j] + bias;
  }
}

// ---------------- K10: in-place IN + ReLU on d_out ----------------
__global__ __launch_bounds__(256) void k_apply(float* __restrict__ out,
                                               const float* __restrict__ scale,
                                               const float* __restrict__ shift) {
  int i = blockIdx.x * 256 + threadIdx.x;   // float4 index, grid exact
  float4* p = (float4*)out;
  float4 v = p[i];
  int bo = (i * 4) / HW;                    // HW divisible by 4 -> uniform within float4
  float sc = scale[bo], sh = shift[bo];
  v.x = fmaxf(0.f, fmaf(v.x, sc, sh));
  v.y = fmaxf(0.f, fmaf(v.y, sc, sh));
  v.z = fmaxf(0.f, fmaf(v.z, sc, sh));
  v.w = fmaxf(0.f, fmaf(v.w, sc, sh));
  p[i] = v;
}

extern "C" void kernel_launch(void* const* d_in, const int* in_sizes, int n_in,
                              void* d_out, int out_size, void* d_ws, size_t ws_size,
                              hipStream_t stream) {
  const float* x  = (const float*)d_in[0];
  const float* W1 = (const float*)d_in[1];
  const float* b1 = (const float*)d_in[2];
  const float* W2 = (const float*)d_in[3];
  const float* b2 = (const float*)d_in[4];
  const float* W3 = (const float*)d_in[5];
  const float* b3 = (const float*)d_in[6];
  float* out = (float*)d_out;

  float* ws = (float*)d_ws;
  float* pooled = ws;                  // 16*256*64      = 262144
  float* Mmat   = ws + 262144;         // 16*256*64      = 262144
  float* invn   = ws + 524288;         // 16*64          = 1024
  float* W3T    = ws + 525312;         // 320*64         = 20480
  float* scale1 = ws + 545792;         // 1024
  float* shift1 = ws + 546816;         // 1024
  float* scale2 = ws + 547840;         // 1024
  float* shift2 = ws + 548864;         // 1024
  float* hpre   = ws + 549888;         // 16*64*9216     = 9437184  (total ~40MB)

  k_pool<<<dim3(BB * CC), dim3(256), 0, stream>>>(x, pooled);
  k_invn<<<dim3(BB), dim3(64), 0, stream>>>(pooled, invn);
  k_M<<<dim3(BB), dim3(256), 0, stream>>>(pooled, invn, W1, Mmat);
  k_w3t<<<dim3(80), dim3(256), 0, stream>>>(W3, W3T);
  k_gemm1<<<dim3(36, BB), dim3(256), 0, stream>>>(x, Mmat, b1, hpre);
  k_stats<<<dim3(BB * 64), dim3(256), 0, stream>>>(hpre, scale1, shift1, 1e-5f);
  k_conv<<<dim3(96, BB), dim3(256), 0, stream>>>(hpre, scale1, shift1, W2, b2, out);
  k_gemm2<<<dim3(36, BB), dim3(256), 0, stream>>>(x, out, W3T, b3, out);
  k_stats<<<dim3(BB * 64), dim3(256), 0, stream>>>(out, scale2, shift2, 1e-5f);
  k_apply<<<dim3(9216), dim3(256), 0, stream>>>(out, scale2, shift2);
}

// Round 2
// 576.869 us; speedup vs baseline: 1.4269x; 1.4269x over previous
//
#include <hip/hip_runtime.h>

#define BB 16
#define CC 256
#define HW 9216   // 96*96

typedef short bf16x8 __attribute__((ext_vector_type(8)));
typedef float f32x4 __attribute__((ext_vector_type(4)));

__device__ __forceinline__ unsigned short f2bf(float f) {
  unsigned u = __float_as_uint(f);
  return (unsigned short)((u + 0x7FFFu + ((u >> 16) & 1u)) >> 16);
}
__device__ __forceinline__ float bf2f(unsigned short h) {
  return __uint_as_float(((unsigned)h) << 16);
}

// ---------------- K1: adaptive avg pool 96x96 -> 8x8 per (b,c) plane ----------------
__global__ __launch_bounds__(256) void k_pool(const float* __restrict__ x,
                                              float* __restrict__ pooled) {
  int bc = blockIdx.x;
  const float* plane = x + (size_t)bc * HW;
  __shared__ float rowwin[96][8];
  for (int idx = threadIdx.x; idx < 96 * 8; idx += 256) {
    int y = idx >> 3, wx = idx & 7;
    const float* r = plane + y * 96 + wx * 12;
    float s = 0.f;
#pragma unroll
    for (int i = 0; i < 12; ++i) s += r[i];
    rowwin[y][wx] = s;
  }
  __syncthreads();
  if (threadIdx.x < 64) {
    int wy = threadIdx.x >> 3, wx = threadIdx.x & 7;
    float s = 0.f;
#pragma unroll
    for (int i = 0; i < 12; ++i) s += rowwin[wy * 12 + i][wx];
    pooled[(size_t)bc * 64 + threadIdx.x] = s * (1.0f / 144.0f);
  }
}

// ---------------- K2: inverse L2 norm over channels of pooled, per (b,p) ----------------
__global__ void k_invn(const float* __restrict__ pooled, float* __restrict__ invn) {
  int b = blockIdx.x;
  int p = threadIdx.x;
  const float* pb = pooled + (size_t)b * CC * 64;
  float s = 0.f;
  for (int c = 0; c < CC; ++c) { float v = pb[c * 64 + p]; s += v * v; }
  invn[b * 64 + p] = 1.0f / fmaxf(sqrtf(s), 1e-12f);
}

// ---------------- K3: M[b][c][o] = sum_p W1[o][p] * ker[b][c][p] ----------------
__global__ __launch_bounds__(256) void k_M(const float* __restrict__ pooled,
                                           const float* __restrict__ invn,
                                           const float* __restrict__ W1,
                                           float* __restrict__ M) {
  int b = blockIdx.x;
  __shared__ float kers[64][256];
  const float* pb = pooled + (size_t)b * CC * 64;
  for (int i = threadIdx.x; i < CC * 64; i += 256) {
    int c = i >> 6, p = i & 63;
    kers[p][c] = pb[i] * invn[b * 64 + p];
  }
  __syncthreads();
  int c = threadIdx.x;
  float* Mb = M + (size_t)b * CC * 64;
  for (int o = 0; o < 64; ++o) {
    float s = 0.f;
#pragma unroll 16
    for (int p = 0; p < 64; ++p) s += W1[o * 64 + p] * kers[p][c];
    Mb[c * 64 + o] = s;
  }
}

// ---------------- K4: prep: W3 transpose, W2 -> bf16 [tap][o][f], zero stats ----------------
__global__ void k_prep(const float* __restrict__ W3, float* __restrict__ W3T,
                       const float* __restrict__ W2, unsigned short* __restrict__ W2bf,
                       float* __restrict__ statsbuf) {
  int i = blockIdx.x * 256 + threadIdx.x;
  if (i < 320 * 64) {
    int c = i >> 6, o = i & 63;
    W3T[i] = W3[o * 320 + c];
  }
  if (i < 9 * 64 * 64) {
    int tap = i >> 12, rem = i & 4095;
    int o = rem >> 6, f = rem & 63;
    W2bf[i] = f2bf(W2[(size_t)(o * 64 + f) * 9 + tap]);
  }
  if (i < 2048) statsbuf[i] = 0.f;
}

// ---------------- K5: gemm1 -> hpix bf16 [b][pix][64 o] + IN stats atomics ----------------
__global__ __launch_bounds__(256) void k_gemm1(const float* __restrict__ x,
                                               const float* __restrict__ M,
                                               const float* __restrict__ b1,
                                               unsigned short* __restrict__ hpix,
                                               float* __restrict__ statsbuf) {
  int tile = blockIdx.x, b = blockIdx.y, t = threadIdx.x;
  int pixbase = tile * 256;
  __shared__ float xs[16][256];
  __shared__ float Ms[16][64];
  __shared__ float ssqs[256];
  const float* xb = x + (size_t)b * CC * HW + pixbase;
  const float* Mb = M + (size_t)b * CC * 64;
  float acc[8][8];
#pragma unroll
  for (int i = 0; i < 8; ++i)
#pragma unroll
    for (int j = 0; j < 8; ++j) acc[i][j] = 0.f;
  float sq = 0.f;
  int to = t >> 5, tp = t & 31;
  for (int c0 = 0; c0 < CC; c0 += 16) {
#pragma unroll
    for (int i = 0; i < 16; ++i) {
      float v = xb[(size_t)(c0 + i) * HW + t];
      xs[i][t] = v;
      sq += v * v;
    }
    for (int i = t; i < 16 * 64; i += 256)
      Ms[i >> 6][i & 63] = Mb[(size_t)(c0 + (i >> 6)) * 64 + (i & 63)];
    __syncthreads();
#pragma unroll
    for (int ci = 0; ci < 16; ++ci) {
      float a[8], xv[8];
#pragma unroll
      for (int i = 0; i < 8; ++i) a[i] = Ms[ci][to * 8 + i];
#pragma unroll
      for (int j = 0; j < 8; ++j) xv[j] = xs[ci][tp + 32 * j];
#pragma unroll
      for (int i = 0; i < 8; ++i)
#pragma unroll
        for (int j = 0; j < 8; ++j) acc[i][j] = fmaf(a[i], xv[j], acc[i][j]);
    }
    __syncthreads();
  }
  ssqs[t] = sq;
  __syncthreads();
  float inv[8];
#pragma unroll
  for (int j = 0; j < 8; ++j)
    inv[j] = 1.0f / fmaxf(sqrtf(ssqs[tp + 32 * j]), 1e-12f);
  float b1v[8];
#pragma unroll
  for (int i = 0; i < 8; ++i) b1v[i] = b1[to * 8 + i];
  float s_o[8], ss_o[8];
#pragma unroll
  for (int i = 0; i < 8; ++i) { s_o[i] = 0.f; ss_o[i] = 0.f; }
#pragma unroll
  for (int j = 0; j < 8; ++j) {
    int pix = pixbase + tp + 32 * j;
    float hv[8];
#pragma unroll
    for (int i = 0; i < 8; ++i) {
      hv[i] = fmaf(acc[i][j], inv[j], b1v[i]);
      s_o[i] += hv[i];
      ss_o[i] += hv[i] * hv[i];
    }
    uint4 pk;
    pk.x = (unsigned)f2bf(hv[0]) | ((unsigned)f2bf(hv[1]) << 16);
    pk.y = (unsigned)f2bf(hv[2]) | ((unsigned)f2bf(hv[3]) << 16);
    pk.z = (unsigned)f2bf(hv[4]) | ((unsigned)f2bf(hv[5]) << 16);
    pk.w = (unsigned)f2bf(hv[6]) | ((unsigned)f2bf(hv[7]) << 16);
    ((uint4*)hpix)[(size_t)((size_t)b * HW + pix) * 8 + to] = pk;
  }
#pragma unroll
  for (int i = 0; i < 8; ++i) {
    float s = s_o[i], ss = ss_o[i];
#pragma unroll
    for (int m = 16; m; m >>= 1) {
      s += __shfl_xor(s, m);
      ss += __shfl_xor(ss, m);
    }
    if (tp == 0) {
      atomicAdd(&statsbuf[(b * 64 + to * 8 + i) * 2], s);
      atomicAdd(&statsbuf[(b * 64 + to * 8 + i) * 2 + 1], ss);
    }
  }
}

// ---------------- K6: finalize IN stats -> scale/shift ----------------
__global__ void k_finalize(const float* __restrict__ statsbuf,
                           float* __restrict__ scale, float* __restrict__ shift) {
  int bo = blockIdx.x * 256 + threadIdx.x;
  if (bo < 1024) {
    float S = statsbuf[bo * 2], SS = statsbuf[bo * 2 + 1];
    float mean = S * (1.0f / (float)HW);
    float var = SS * (1.0f / (float)HW) - mean * mean;
    float rstd = rsqrtf(var + 1e-5f);
    scale[bo] = rstd;
    shift[bo] = -mean * rstd;
  }
}

// ---------------- K7: conv3x3 via MFMA implicit GEMM -> hh fp32 (in d_out) ----------------
__global__ __launch_bounds__(256) void k_conv_mfma(
    const unsigned short* __restrict__ hpix,
    const float* __restrict__ scale1, const float* __restrict__ shift1,
    const unsigned short* __restrict__ W2bf, const float* __restrict__ b2,
    float* __restrict__ hh) {
  int band = blockIdx.x;              // 0..23 (4 rows each)
  int b = blockIdx.y;
  int t = threadIdx.x;
  int w = t >> 6;                     // wave 0..3 -> output row band*4+w
  int lane = t & 63;
  int l15 = lane & 15, l4 = lane >> 4;
  int y = band * 4 + w;

  __shared__ unsigned short hs[6 * 98 * 32];  // [r0..5][x0..97][32 f] bf16, granule-swizzled
  __shared__ float scs[64], shs[64];
  if (t < 64) { scs[t] = scale1[b * 64 + t]; shs[t] = shift1[b * 64 + t]; }

  f32x4 acc[4][6];
#pragma unroll
  for (int mf = 0; mf < 4; ++mf)
#pragma unroll
    for (int nf = 0; nf < 6; ++nf) {
      f32x4 z = {0.f, 0.f, 0.f, 0.f};
      acc[mf][nf] = z;
    }

  for (int f0 = 0; f0 < 64; f0 += 32) {
    __syncthreads();
    // stage 6 rows x 98 cols x 32 f (normalized+relu, bf16, swizzled granules)
    for (int idx = t; idx < 6 * 98 * 8; idx += 256) {
      int f4 = idx & 7;               // 4-f group within 32-f chunk
      int v = idx >> 3;
      int xr = v % 98;
      int r = v / 98;
      int gy = band * 4 - 1 + r;
      int gx = xr - 1;
      unsigned pk0 = 0, pk1 = 0;
      if ((unsigned)gy < 96u && (unsigned)gx < 96u) {
        const ushort4 rv = *(const ushort4*)(hpix +
            ((size_t)((size_t)b * HW + gy * 96 + gx) * 64 + f0 + f4 * 4));
        int fb = f0 + f4 * 4;
        float v0 = fmaxf(0.f, fmaf(bf2f(rv.x), scs[fb],     shs[fb]));
        float v1 = fmaxf(0.f, fmaf(bf2f(rv.y), scs[fb + 1], shs[fb + 1]));
        float v2 = fmaxf(0.f, fmaf(bf2f(rv.z), scs[fb + 2], shs[fb + 2]));
        float v3 = fmaxf(0.f, fmaf(bf2f(rv.w), scs[fb + 3], shs[fb + 3]));
        pk0 = (unsigned)f2bf(v0) | ((unsigned)f2bf(v1) << 16);
        pk1 = (unsigned)f2bf(v2) | ((unsigned)f2bf(v3) << 16);
      }
      int g = f4 >> 1;
      int gs = g ^ ((xr >> 1) & 3);
      unsigned loff = (unsigned)((r * 98 + xr) * 64 + gs * 16 + (f4 & 1) * 8);
      *(uint2*)((char*)hs + loff) = make_uint2(pk0, pk1);
    }
    __syncthreads();
    // compute: 9 taps x 24 MFMA per 32-f chunk
#pragma unroll
    for (int dy = 0; dy < 3; ++dy) {
      int r = w + dy;
#pragma unroll
      for (int dx = 0; dx < 3; ++dx) {
        int tap = dy * 3 + dx;
        bf16x8 afr[4];
#pragma unroll
        for (int mf = 0; mf < 4; ++mf) {
          int o = mf * 16 + l15;
          afr[mf] = *(const bf16x8*)(W2bf + ((size_t)(tap * 64 + o) * 64 + f0 + l4 * 8));
        }
#pragma unroll
        for (int nf = 0; nf < 6; ++nf) {
          int xr = nf * 16 + l15 + dx;           // LDS x = pixel + dx (halo offset folded)
          unsigned loff = (unsigned)((r * 98 + xr) * 64 + ((l4 ^ ((xr >> 1) & 3)) * 16));
          bf16x8 bfr = *(const bf16x8*)((const char*)hs + loff);
#pragma unroll
          for (int mf = 0; mf < 4; ++mf)
            acc[mf][nf] = __builtin_amdgcn_mfma_f32_16x16x32_bf16(
                afr[mf], bfr, acc[mf][nf], 0, 0, 0);
        }
      }
    }
  }
  // epilogue: D col=lane&15 (pixel), row=(lane>>4)*4+i (o)
#pragma unroll
  for (int mf = 0; mf < 4; ++mf) {
    int o = mf * 16 + l4 * 4;
#pragma unroll
    for (int i = 0; i < 4; ++i) {
      float bias = b2[o + i];
#pragma unroll
      for (int nf = 0; nf < 6; ++nf) {
        hh[(size_t)((size_t)b * 64 + o + i) * HW + y * 96 + nf * 16 + l15] =
            acc[mf][nf][i] + bias;
      }
    }
  }
}

// ---------------- K8: out_pre = W3a·x + W3b·hh + b3  (hh and outp both = d_out) ----------------
__global__ __launch_bounds__(256) void k_gemm2(const float* __restrict__ x,
                                               const float* hh,
                                               const float* __restrict__ W3T,
                                               const float* __restrict__ b3,
                                               float* outp) {
  int tile = blockIdx.x, b = blockIdx.y, t = threadIdx.x;
  int pixbase = tile * 256;
  __shared__ float xs[16][256];
  __shared__ float Ws[16][64];
  const float* xb = x + (size_t)b * CC * HW + pixbase;
  const float* hb = hh + (size_t)b * 64 * HW + pixbase;
  float acc[8][8];
#pragma unroll
  for (int i = 0; i < 8; ++i)
#pragma unroll
    for (int j = 0; j < 8; ++j) acc[i][j] = 0.f;
  int to = t >> 5, tp = t & 31;
  for (int k0 = 0; k0 < 320; k0 += 16) {
    const float* src = (k0 < 256) ? (xb + (size_t)k0 * HW) : (hb + (size_t)(k0 - 256) * HW);
#pragma unroll
    for (int i = 0; i < 16; ++i) xs[i][t] = src[(size_t)i * HW + t];
    for (int i = t; i < 16 * 64; i += 256)
      Ws[i >> 6][i & 63] = W3T[(size_t)(k0 + (i >> 6)) * 64 + (i & 63)];
    __syncthreads();
#pragma unroll
    for (int ci = 0; ci < 16; ++ci) {
      float a[8], xv[8];
#pragma unroll
      for (int i = 0; i < 8; ++i) a[i] = Ws[ci][to * 8 + i];
#pragma unroll
      for (int j = 0; j < 8; ++j) xv[j] = xs[ci][tp + 32 * j];
#pragma unroll
      for (int i = 0; i < 8; ++i)
#pragma unroll
        for (int j = 0; j < 8; ++j) acc[i][j] = fmaf(a[i], xv[j], acc[i][j]);
    }
    __syncthreads();
  }
#pragma unroll
  for (int i = 0; i < 8; ++i) {
    int o = to * 8 + i;
    float bias = b3[o];
    float* dst = outp + ((size_t)b * 64 + o) * HW + pixbase;
#pragma unroll
    for (int j = 0; j < 8; ++j) dst[tp + 32 * j] = acc[i][j] + bias;
  }
}

// ---------------- K9: instance-norm stats per (b,o) ----------------
__global__ __launch_bounds__(256) void k_stats(const float* __restrict__ src,
                                               float* __restrict__ scale,
                                               float* __restrict__ shift,
                                               float eps) {
  int bo = blockIdx.x;
  const float* p = src + (size_t)bo * HW;
  float s = 0.f, ss = 0.f;
  for (int i = threadIdx.x; i < HW; i += 256) {
    float v = p[i];
    s += v;
    ss += v * v;
  }
  __shared__ float sh[8];
  int lane = threadIdx.x & 63, w = threadIdx.x >> 6;
#pragma unroll
  for (int off = 32; off; off >>= 1) {
    s += __shfl_down(s, off);
    ss += __shfl_down(ss, off);
  }
  if (lane == 0) { sh[w] = s; sh[4 + w] = ss; }
  __syncthreads();
  if (threadIdx.x == 0) {
    float S = sh[0] + sh[1] + sh[2] + sh[3];
    float SS = sh[4] + sh[5] + sh[6] + sh[7];
    float mean = S * (1.0f / (float)HW);
    float var = SS * (1.0f / (float)HW) - mean * mean;
    float rstd = rsqrtf(var + eps);
    scale[bo] = rstd;
    shift[bo] = -mean * rstd;
  }
}

// ---------------- K10: in-place IN + ReLU on d_out ----------------
__global__ __launch_bounds__(256) void k_apply(float* __restrict__ out,
                                               const float* __restrict__ scale,
                                               const float* __restrict__ shift) {
  int i = blockIdx.x * 256 + threadIdx.x;
  float4* p = (float4*)out;
  float4 v = p[i];
  int bo = (i * 4) / HW;
  float sc = scale[bo], sh = shift[bo];
  v.x = fmaxf(0.f, fmaf(v.x, sc, sh));
  v.y = fmaxf(0.f, fmaf(v.y, sc, sh));
  v.z = fmaxf(0.f, fmaf(v.z, sc, sh));
  v.w = fmaxf(0.f, fmaf(v.w, sc, sh));
  p[i] = v;
}

extern "C" void kernel_launch(void* const* d_in, const int* in_sizes, int n_in,
                              void* d_out, int out_size, void* d_ws, size_t ws_size,
                              hipStream_t stream) {
  const float* x  = (const float*)d_in[0];
  const float* W1 = (const float*)d_in[1];
  const float* b1 = (const float*)d_in[2];
  const float* W2 = (const float*)d_in[3];
  const float* b2 = (const float*)d_in[4];
  const float* W3 = (const float*)d_in[5];
  const float* b3 = (const float*)d_in[6];
  float* out = (float*)d_out;

  float* ws = (float*)d_ws;
  float* pooled = ws;                          // 262144
  float* Mmat   = ws + 262144;                 // 262144
  float* invn   = ws + 524288;                 // 1024
  float* W3T    = ws + 525312;                 // 20480
  float* scale1 = ws + 545792;                 // 1024
  float* shift1 = ws + 546816;                 // 1024
  float* scale2 = ws + 547840;                 // 1024
  float* shift2 = ws + 548864;                 // 1024
  float* stats  = ws + 549888;                 // 2048
  unsigned short* W2bf = (unsigned short*)(ws + 551936);   // 36864 ushort (18432 f)
  unsigned short* hpix = (unsigned short*)(ws + 570368);   // 16*9216*64 bf16 (4718592 f)

  k_prep<<<dim3(144), dim3(256), 0, stream>>>(W3, W3T, W2, W2bf, stats);
  k_pool<<<dim3(BB * CC), dim3(256), 0, stream>>>(x, pooled);
  k_invn<<<dim3(BB), dim3(64), 0, stream>>>(pooled, invn);
  k_M<<<dim3(BB), dim3(256), 0, stream>>>(pooled, invn, W1, Mmat);
  k_gemm1<<<dim3(36, BB), dim3(256), 0, stream>>>(x, Mmat, b1, hpix, stats);
  k_finalize<<<dim3(4), dim3(256), 0, stream>>>(stats, scale1, shift1);
  k_conv_mfma<<<dim3(24, BB), dim3(256), 0, stream>>>(hpix, scale1, shift1, W2bf, b2, out);
  k_gemm2<<<dim3(36, BB), dim3(256), 0, stream>>>(x, out, W3T, b3, out);
  k_stats<<<dim3(BB * 64), dim3(256), 0, stream>>>(out, scale2, shift2, 1e-5f);
  k_apply<<<dim3(9216), dim3(256), 0, stream>>>(out, scale2, shift2);
}

// Round 3
// 307.413 us; speedup vs baseline: 2.6776x; 1.8765x over previous
//
#include <hip/hip_runtime.h>

#define BB 16
#define CC 256
#define HW 9216   // 96*96

typedef short bf16x8 __attribute__((ext_vector_type(8)));
typedef float f32x4 __attribute__((ext_vector_type(4)));

__device__ __forceinline__ unsigned short f2bf(float f) {
  unsigned u = __float_as_uint(f);
  return (unsigned short)((u + 0x7FFFu + ((u >> 16) & 1u)) >> 16);
}
__device__ __forceinline__ float bf2f(unsigned short h) {
  return __uint_as_float(((unsigned)h) << 16);
}

// ---------------- K1: adaptive avg pool 96x96 -> 8x8 per (b,c) plane ----------------
__global__ __launch_bounds__(256) void k_pool(const float* __restrict__ x,
                                              float* __restrict__ pooled) {
  int bc = blockIdx.x;
  const float* plane = x + (size_t)bc * HW;
  __shared__ float rowwin[96][8];
  for (int idx = threadIdx.x; idx < 96 * 8; idx += 256) {
    int y = idx >> 3, wx = idx & 7;
    const float* r = plane + y * 96 + wx * 12;
    float s = 0.f;
#pragma unroll
    for (int i = 0; i < 12; ++i) s += r[i];
    rowwin[y][wx] = s;
  }
  __syncthreads();
  if (threadIdx.x < 64) {
    int wy = threadIdx.x >> 3, wx = threadIdx.x & 7;
    float s = 0.f;
#pragma unroll
    for (int i = 0; i < 12; ++i) s += rowwin[wy * 12 + i][wx];
    pooled[(size_t)bc * 64 + threadIdx.x] = s * (1.0f / 144.0f);
  }
}

// ---------------- K2: inverse L2 norm over channels of pooled, per (b,p) ----------------
__global__ void k_invn(const float* __restrict__ pooled, float* __restrict__ invn) {
  int b = blockIdx.x;
  int p = threadIdx.x;
  const float* pb = pooled + (size_t)b * CC * 64;
  float s = 0.f;
  for (int c = 0; c < CC; ++c) { float v = pb[c * 64 + p]; s += v * v; }
  invn[b * 64 + p] = 1.0f / fmaxf(sqrtf(s), 1e-12f);
}

// ---------------- K3: Mbf[b][o][c] = bf16( sum_p W1[o][p] * ker[b][c][p] ) ----------------
__global__ __launch_bounds__(256) void k_M(const float* __restrict__ pooled,
                                           const float* __restrict__ invn,
                                           const float* __restrict__ W1,
                                           unsigned short* __restrict__ Mbf) {
  int b = blockIdx.x;
  __shared__ float kers[64][256];
  const float* pb = pooled + (size_t)b * CC * 64;
  for (int i = threadIdx.x; i < CC * 64; i += 256) {
    int c = i >> 6, p = i & 63;
    kers[p][c] = pb[i] * invn[b * 64 + p];
  }
  __syncthreads();
  int c = threadIdx.x;
  unsigned short* Mb = Mbf + (size_t)b * 64 * 256;
  for (int o = 0; o < 64; ++o) {
    float s = 0.f;
#pragma unroll 16
    for (int p = 0; p < 64; ++p) s += W1[o * 64 + p] * kers[p][c];
    Mb[o * 256 + c] = f2bf(s);
  }
}

// ---------------- K4: prep: W3 -> bf16 [o][320], W2 -> bf16 [tap][o][f], zero stats ----------------
__global__ void k_prep(const float* __restrict__ W3, unsigned short* __restrict__ W3bf,
                       const float* __restrict__ W2, unsigned short* __restrict__ W2bf,
                       float* __restrict__ statsbuf) {
  int i = blockIdx.x * 256 + threadIdx.x;
  if (i < 64 * 320) W3bf[i] = f2bf(W3[i]);
  if (i < 9 * 64 * 64) {
    int tap = i >> 12, rem = i & 4095;
    int o = rem >> 6, f = rem & 63;
    W2bf[i] = f2bf(W2[(size_t)(o * 64 + f) * 9 + tap]);
  }
  if (i < 4096) statsbuf[i] = 0.f;
}

// ---------------- K5: transpose x -> xT bf16 [b][pix][256c] + ssq[b][pix] ----------------
__global__ __launch_bounds__(256) void k_trans(const float* __restrict__ x,
                                               unsigned short* __restrict__ xT,
                                               float* __restrict__ ssq) {
  int b = blockIdx.y;
  int px0 = blockIdx.x * 64;
  int t = threadIdx.x;
  int px = t & 63, cg = t >> 6;            // 64 pixels x 4 channel-groups
  __shared__ unsigned char sm[32768];      // [64 px][256 c] bf16, 16B-swizzled
  __shared__ float sq[64];
  if (t < 64) sq[t] = 0.f;
  __syncthreads();
  float part = 0.f;
  const float* xb = x + (size_t)b * CC * HW + px0 + px;
#pragma unroll
  for (int kk = 0; kk < 8; ++kk) {
    int c = cg * 64 + kk * 8;
    float v[8];
#pragma unroll
    for (int j = 0; j < 8; ++j) {
      v[j] = xb[(size_t)(c + j) * HW];
      part += v[j] * v[j];
    }
    uint4 pk;
    pk.x = (unsigned)f2bf(v[0]) | ((unsigned)f2bf(v[1]) << 16);
    pk.y = (unsigned)f2bf(v[2]) | ((unsigned)f2bf(v[3]) << 16);
    pk.z = (unsigned)f2bf(v[4]) | ((unsigned)f2bf(v[5]) << 16);
    pk.w = (unsigned)f2bf(v[6]) | ((unsigned)f2bf(v[7]) << 16);
    int u = cg * 8 + kk;                   // 16B unit within 512B pixel row
    *(uint4*)(sm + px * 512 + ((u ^ (px & 31)) << 4)) = pk;
  }
  atomicAdd(&sq[px], part);
  __syncthreads();
  uint4* dst = (uint4*)(xT + ((size_t)b * HW + px0) * 256);
  for (int i = t; i < 2048; i += 256) {
    int p = i >> 5, q = i & 31;
    dst[i] = *(const uint4*)(sm + p * 512 + ((q ^ (p & 31)) << 4));
  }
  if (t < 64) ssq[(size_t)b * HW + px0 + t] = sq[t];
}

// ---------------- K6: gemm1 MFMA: h = invn*(M·x) + b1 -> hpix bf16 [b][pix][64] + stats ----------------
__global__ __launch_bounds__(256) void k_gemm1(
    const unsigned short* __restrict__ xT,
    const unsigned short* __restrict__ Mbf,
    const float* __restrict__ ssq,
    const float* __restrict__ b1,
    unsigned short* __restrict__ hpix,
    float* __restrict__ stats1) {
  int tile = blockIdx.x, b = blockIdx.y, t = threadIdx.x;
  int w = t >> 6, lane = t & 63, l15 = lane & 15, l4 = lane >> 4;
  int pixbase = tile * 256;
  __shared__ unsigned char Alds[32768];    // A: [64 o][256 c] bf16 swizzled; reused as epi tile
  __shared__ float sb[128];
  {
    const uint4* src = (const uint4*)(Mbf + (size_t)b * 64 * 256);
    for (int i = t; i < 2048; i += 256) {
      int o = i >> 5, u = i & 31;
      *(uint4*)(Alds + o * 512 + ((u ^ (o & 7)) << 4)) = src[i];
    }
  }
  if (t < 128) sb[t] = 0.f;
  __syncthreads();
  f32x4 acc[4][4];
#pragma unroll
  for (int mf = 0; mf < 4; ++mf)
#pragma unroll
    for (int nf = 0; nf < 4; ++nf) { f32x4 z = {0.f,0.f,0.f,0.f}; acc[mf][nf] = z; }
  const unsigned short* xrow = xT + ((size_t)b * HW + pixbase + w * 64) * 256;
#pragma unroll
  for (int kk = 0; kk < 8; ++kk) {
    bf16x8 afr[4], bfr[4];
    int u = kk * 4 + l4;
#pragma unroll
    for (int mf = 0; mf < 4; ++mf)
      afr[mf] = *(const bf16x8*)(Alds + (mf * 16 + l15) * 512 + ((u ^ (l15 & 7)) << 4));
#pragma unroll
    for (int nf = 0; nf < 4; ++nf)
      bfr[nf] = *(const bf16x8*)(xrow + (size_t)(nf * 16 + l15) * 256 + kk * 32 + l4 * 8);
#pragma unroll
    for (int mf = 0; mf < 4; ++mf)
#pragma unroll
      for (int nf = 0; nf < 4; ++nf)
        acc[mf][nf] = __builtin_amdgcn_mfma_f32_16x16x32_bf16(afr[mf], bfr[nf], acc[mf][nf], 0, 0, 0);
  }
  // epilogue
  float invs[4];
  const float* ssqb = ssq + (size_t)b * HW + pixbase + w * 64;
#pragma unroll
  for (int nf = 0; nf < 4; ++nf)
    invs[nf] = 1.0f / fmaxf(sqrtf(ssqb[nf * 16 + l15]), 1e-12f);
  float b1v[4][4];
#pragma unroll
  for (int mf = 0; mf < 4; ++mf)
#pragma unroll
    for (int i = 0; i < 4; ++i) b1v[mf][i] = b1[mf * 16 + l4 * 4 + i];
  float s_acc[4][4], ss_acc[4][4];
#pragma unroll
  for (int mf = 0; mf < 4; ++mf)
#pragma unroll
    for (int i = 0; i < 4; ++i) { s_acc[mf][i] = 0.f; ss_acc[mf][i] = 0.f; }
  __syncthreads();                          // A reads done; reuse Alds as [256px][64o] tile
#pragma unroll
  for (int mf = 0; mf < 4; ++mf)
#pragma unroll
    for (int nf = 0; nf < 4; ++nf) {
      float hv[4];
#pragma unroll
      for (int i = 0; i < 4; ++i) {
        hv[i] = fmaf(acc[mf][nf][i], invs[nf], b1v[mf][i]);
        s_acc[mf][i] += hv[i];
        ss_acc[mf][i] += hv[i] * hv[i];
      }
      uint2 pk;
      pk.x = (unsigned)f2bf(hv[0]) | ((unsigned)f2bf(hv[1]) << 16);
      pk.y = (unsigned)f2bf(hv[2]) | ((unsigned)f2bf(hv[3]) << 16);
      int px = w * 64 + nf * 16 + l15;
      int v = mf * 4 + l4;                  // 8B unit within 128B pixel row
      *(uint2*)(Alds + px * 128 + ((v ^ ((px & 7) << 1)) << 3)) = pk;
    }
#pragma unroll
  for (int mf = 0; mf < 4; ++mf)
#pragma unroll
    for (int i = 0; i < 4; ++i) {
      float s = s_acc[mf][i], q = ss_acc[mf][i];
#pragma unroll
      for (int m = 1; m < 16; m <<= 1) {
        s += __shfl_xor(s, m);
        q += __shfl_xor(q, m);
      }
      if (l15 == 0) {
        int o = mf * 16 + l4 * 4 + i;
        atomicAdd(&sb[o * 2], s);
        atomicAdd(&sb[o * 2 + 1], q);
      }
    }
  __syncthreads();
  uint4* dst = (uint4*)(hpix + ((size_t)b * HW + pixbase) * 64);
  for (int i = t; i < 2048; i += 256) {
    int p = i >> 3, u16 = i & 7;
    dst[i] = *(const uint4*)(Alds + p * 128 + ((u16 ^ (p & 7)) << 4));
  }
  if (t < 64) {
    atomicAdd(&stats1[(b * 64 + t) * 2], sb[t * 2]);
    atomicAdd(&stats1[(b * 64 + t) * 2 + 1], sb[t * 2 + 1]);
  }
}

// ---------------- K7: finalize IN stats -> scale/shift ----------------
__global__ void k_finalize(const float* __restrict__ statsbuf,
                           float* __restrict__ scale, float* __restrict__ shift) {
  int bo = blockIdx.x * 256 + threadIdx.x;
  if (bo < 1024) {
    float S = statsbuf[bo * 2], SS = statsbuf[bo * 2 + 1];
    float mean = S * (1.0f / (float)HW);
    float var = SS * (1.0f / (float)HW) - mean * mean;
    float rstd = rsqrtf(var + 1e-5f);
    scale[bo] = rstd;
    shift[bo] = -mean * rstd;
  }
}

// ---------------- K8: conv3x3 MFMA -> hh bf16 pixel-major [b][pix][64] (in d_out) ----------------
__global__ __launch_bounds__(256) void k_conv_mfma(
    const unsigned short* __restrict__ hpix,
    const float* __restrict__ scale1, const float* __restrict__ shift1,
    const unsigned short* __restrict__ W2bf, const float* __restrict__ b2,
    unsigned short* __restrict__ hh) {
  int band = blockIdx.x;              // 0..23 (4 rows each)
  int b = blockIdx.y;
  int t = threadIdx.x;
  int w = t >> 6;
  int lane = t & 63;
  int l15 = lane & 15, l4 = lane >> 4;

  __shared__ unsigned char smem[49152];  // hs (37.6KB) then reused as epi tile (48KB)
  unsigned short* hs = (unsigned short*)smem;
  __shared__ float scs[64], shs[64];
  if (t < 64) { scs[t] = scale1[b * 64 + t]; shs[t] = shift1[b * 64 + t]; }

  f32x4 acc[4][6];
#pragma unroll
  for (int mf = 0; mf < 4; ++mf)
#pragma unroll
    for (int nf = 0; nf < 6; ++nf) { f32x4 z = {0.f,0.f,0.f,0.f}; acc[mf][nf] = z; }

  for (int f0 = 0; f0 < 64; f0 += 32) {
    __syncthreads();
    for (int idx = t; idx < 6 * 98 * 8; idx += 256) {
      int f4 = idx & 7;
      int v = idx >> 3;
      int xr = v % 98;
      int r = v / 98;
      int gy = band * 4 - 1 + r;
      int gx = xr - 1;
      unsigned pk0 = 0, pk1 = 0;
      if ((unsigned)gy < 96u && (unsigned)gx < 96u) {
        const ushort4 rv = *(const ushort4*)(hpix +
            ((size_t)((size_t)b * HW + gy * 96 + gx) * 64 + f0 + f4 * 4));
        int fb = f0 + f4 * 4;
        float v0 = fmaxf(0.f, fmaf(bf2f(rv.x), scs[fb],     shs[fb]));
        float v1 = fmaxf(0.f, fmaf(bf2f(rv.y), scs[fb + 1], shs[fb + 1]));
        float v2 = fmaxf(0.f, fmaf(bf2f(rv.z), scs[fb + 2], shs[fb + 2]));
        float v3 = fmaxf(0.f, fmaf(bf2f(rv.w), scs[fb + 3], shs[fb + 3]));
        pk0 = (unsigned)f2bf(v0) | ((unsigned)f2bf(v1) << 16);
        pk1 = (unsigned)f2bf(v2) | ((unsigned)f2bf(v3) << 16);
      }
      int g = f4 >> 1;
      int gs = g ^ ((xr >> 1) & 3);
      unsigned loff = (unsigned)((r * 98 + xr) * 64 + gs * 16 + (f4 & 1) * 8);
      *(uint2*)(smem + loff) = make_uint2(pk0, pk1);
    }
    __syncthreads();
#pragma unroll
    for (int dy = 0; dy < 3; ++dy) {
      int r = w + dy;
#pragma unroll
      for (int dx = 0; dx < 3; ++dx) {
        int tap = dy * 3 + dx;
        bf16x8 afr[4];
#pragma unroll
        for (int mf = 0; mf < 4; ++mf) {
          int o = mf * 16 + l15;
          afr[mf] = *(const bf16x8*)(W2bf + ((size_t)(tap * 64 + o) * 64 + f0 + l4 * 8));
        }
#pragma unroll
        for (int nf = 0; nf < 6; ++nf) {
          int xr = nf * 16 + l15 + dx;
          unsigned loff = (unsigned)((r * 98 + xr) * 64 + ((l4 ^ ((xr >> 1) & 3)) * 16));
          bf16x8 bfr = *(const bf16x8*)(smem + loff);
#pragma unroll
          for (int mf = 0; mf < 4; ++mf)
            acc[mf][nf] = __builtin_amdgcn_mfma_f32_16x16x32_bf16(
                afr[mf], bfr, acc[mf][nf], 0, 0, 0);
        }
      }
    }
  }
  // epilogue: pack bf16 pixel-major via LDS tile [384 px][64 o]
  float b2v[4][4];
#pragma unroll
  for (int mf = 0; mf < 4; ++mf)
#pragma unroll
    for (int i = 0; i < 4; ++i) b2v[mf][i] = b2[mf * 16 + l4 * 4 + i];
  __syncthreads();
#pragma unroll
  for (int mf = 0; mf < 4; ++mf)
#pragma unroll
    for (int nf = 0; nf < 6; ++nf) {
      int tpx = w * 96 + nf * 16 + l15;
      float h0 = acc[mf][nf][0] + b2v[mf][0];
      float h1 = acc[mf][nf][1] + b2v[mf][1];
      float h2 = acc[mf][nf][2] + b2v[mf][2];
      float h3 = acc[mf][nf][3] + b2v[mf][3];
      uint2 pk;
      pk.x = (unsigned)f2bf(h0) | ((unsigned)f2bf(h1) << 16);
      pk.y = (unsigned)f2bf(h2) | ((unsigned)f2bf(h3) << 16);
      int v = mf * 4 + l4;
      *(uint2*)(smem + tpx * 128 + ((v ^ ((tpx & 7) << 1)) << 3)) = pk;
    }
  __syncthreads();
  uint4* dst = (uint4*)(hh + ((size_t)b * HW + band * 384) * 64);
  for (int i = t; i < 3072; i += 256) {
    int p = i >> 3, u16 = i & 7;
    dst[i] = *(const uint4*)(smem + p * 128 + ((u16 ^ (p & 7)) << 4));
  }
}

// ---------------- K9: gemm2 MFMA: outpre = W3·cat(x,hh) + b3 -> opre bf16 + stats ----------------
__global__ __launch_bounds__(256) void k_gemm2(
    const unsigned short* __restrict__ xT,
    const unsigned short* __restrict__ hh,
    const unsigned short* __restrict__ W3bf,
    const float* __restrict__ b3,
    unsigned short* __restrict__ opre,
    float* __restrict__ stats2) {
  int tile = blockIdx.x, b = blockIdx.y, t = threadIdx.x;
  int w = t >> 6, lane = t & 63, l15 = lane & 15, l4 = lane >> 4;
  int pixbase = tile * 256;
  __shared__ unsigned char Alds[40960];    // A: [64 o][320 c] bf16 swizzled; reused as epi tile
  __shared__ float sb[128];
  {
    const uint4* src = (const uint4*)W3bf;
    for (int i = t; i < 2560; i += 256) {
      int o = i / 40, u = i - o * 40;
      *(uint4*)(Alds + o * 640 + ((u ^ (o & 7)) << 4)) = src[i];
    }
  }
  if (t < 128) sb[t] = 0.f;
  __syncthreads();
  f32x4 acc[4][4];
#pragma unroll
  for (int mf = 0; mf < 4; ++mf)
#pragma unroll
    for (int nf = 0; nf < 4; ++nf) { f32x4 z = {0.f,0.f,0.f,0.f}; acc[mf][nf] = z; }
  const unsigned short* xrow = xT + ((size_t)b * HW + pixbase + w * 64) * 256;
  const unsigned short* hrow = hh + ((size_t)b * HW + pixbase + w * 64) * 64;
#pragma unroll
  for (int kk = 0; kk < 8; ++kk) {
    bf16x8 afr[4], bfr[4];
    int u = kk * 4 + l4;
#pragma unroll
    for (int mf = 0; mf < 4; ++mf)
      afr[mf] = *(const bf16x8*)(Alds + (mf * 16 + l15) * 640 + ((u ^ (l15 & 7)) << 4));
#pragma unroll
    for (int nf = 0; nf < 4; ++nf)
      bfr[nf] = *(const bf16x8*)(xrow + (size_t)(nf * 16 + l15) * 256 + kk * 32 + l4 * 8);
#pragma unroll
    for (int mf = 0; mf < 4; ++mf)
#pragma unroll
      for (int nf = 0; nf < 4; ++nf)
        acc[mf][nf] = __builtin_amdgcn_mfma_f32_16x16x32_bf16(afr[mf], bfr[nf], acc[mf][nf], 0, 0, 0);
  }
#pragma unroll
  for (int kk = 8; kk < 10; ++kk) {
    bf16x8 afr[4], bfr[4];
    int u = kk * 4 + l4;
#pragma unroll
    for (int mf = 0; mf < 4; ++mf)
      afr[mf] = *(const bf16x8*)(Alds + (mf * 16 + l15) * 640 + ((u ^ (l15 & 7)) << 4));
#pragma unroll
    for (int nf = 0; nf < 4; ++nf)
      bfr[nf] = *(const bf16x8*)(hrow + (size_t)(nf * 16 + l15) * 64 + (kk - 8) * 32 + l4 * 8);
#pragma unroll
    for (int mf = 0; mf < 4; ++mf)
#pragma unroll
      for (int nf = 0; nf < 4; ++nf)
        acc[mf][nf] = __builtin_amdgcn_mfma_f32_16x16x32_bf16(afr[mf], bfr[nf], acc[mf][nf], 0, 0, 0);
  }
  float b3v[4][4];
#pragma unroll
  for (int mf = 0; mf < 4; ++mf)
#pragma unroll
    for (int i = 0; i < 4; ++i) b3v[mf][i] = b3[mf * 16 + l4 * 4 + i];
  float s_acc[4][4], ss_acc[4][4];
#pragma unroll
  for (int mf = 0; mf < 4; ++mf)
#pragma unroll
    for (int i = 0; i < 4; ++i) { s_acc[mf][i] = 0.f; ss_acc[mf][i] = 0.f; }
  __syncthreads();
#pragma unroll
  for (int mf = 0; mf < 4; ++mf)
#pragma unroll
    for (int nf = 0; nf < 4; ++nf) {
      float hv[4];
#pragma unroll
      for (int i = 0; i < 4; ++i) {
        hv[i] = acc[mf][nf][i] + b3v[mf][i];
        s_acc[mf][i] += hv[i];
        ss_acc[mf][i] += hv[i] * hv[i];
      }
      uint2 pk;
      pk.x = (unsigned)f2bf(hv[0]) | ((unsigned)f2bf(hv[1]) << 16);
      pk.y = (unsigned)f2bf(hv[2]) | ((unsigned)f2bf(hv[3]) << 16);
      int px = w * 64 + nf * 16 + l15;
      int v = mf * 4 + l4;
      *(uint2*)(Alds + px * 128 + ((v ^ ((px & 7) << 1)) << 3)) = pk;
    }
#pragma unroll
  for (int mf = 0; mf < 4; ++mf)
#pragma unroll
    for (int i = 0; i < 4; ++i) {
      float s = s_acc[mf][i], q = ss_acc[mf][i];
#pragma unroll
      for (int m = 1; m < 16; m <<= 1) {
        s += __shfl_xor(s, m);
        q += __shfl_xor(q, m);
      }
      if (l15 == 0) {
        int o = mf * 16 + l4 * 4 + i;
        atomicAdd(&sb[o * 2], s);
        atomicAdd(&sb[o * 2 + 1], q);
      }
    }
  __syncthreads();
  uint4* dst = (uint4*)(opre + ((size_t)b * HW + pixbase) * 64);
  for (int i = t; i < 2048; i += 256) {
    int p = i >> 3, u16 = i & 7;
    dst[i] = *(const uint4*)(Alds + p * 128 + ((u16 ^ (p & 7)) << 4));
  }
  if (t < 64) {
    atomicAdd(&stats2[(b * 64 + t) * 2], sb[t * 2]);
    atomicAdd(&stats2[(b * 64 + t) * 2 + 1], sb[t * 2 + 1]);
  }
}

// ---------------- K10: apply IN+ReLU, transpose to o-major fp32 d_out ----------------
__global__ __launch_bounds__(256) void k_apply(const unsigned short* __restrict__ opre,
                                               const float* __restrict__ scale,
                                               const float* __restrict__ shift,
                                               float* __restrict__ out) {
  int b = blockIdx.y, px0 = blockIdx.x * 64, t = threadIdx.x;
  __shared__ float tile[64][68];
  __shared__ float scs[64], shs[64];
  if (t < 64) { scs[t] = scale[b * 64 + t]; shs[t] = shift[b * 64 + t]; }
  __syncthreads();
  const unsigned* src = (const unsigned*)(opre + ((size_t)b * HW + px0) * 64);
  for (int i = t; i < 2048; i += 256) {
    int px = i >> 5, q = i & 31;
    unsigned v = src[i];
    int o = q * 2;
    float f0 = bf2f((unsigned short)(v & 0xffff));
    float f1 = bf2f((unsigned short)(v >> 16));
    tile[o][px]     = fmaxf(0.f, fmaf(f0, scs[o], shs[o]));
    tile[o + 1][px] = fmaxf(0.f, fmaf(f1, scs[o + 1], shs[o + 1]));
  }
  __syncthreads();
  for (int j = t; j < 1024; j += 256) {
    int o = j >> 4, w4 = j & 15;
    float4 v = *(const float4*)(&tile[o][w4 * 4]);
    *(float4*)(out + ((size_t)(b * 64) + o) * HW + px0 + w4 * 4) = v;
  }
}

extern "C" void kernel_launch(void* const* d_in, const int* in_sizes, int n_in,
                              void* d_out, int out_size, void* d_ws, size_t ws_size,
                              hipStream_t stream) {
  const float* x  = (const float*)d_in[0];
  const float* W1 = (const float*)d_in[1];
  const float* b1 = (const float*)d_in[2];
  const float* W2 = (const float*)d_in[3];
  const float* b2 = (const float*)d_in[4];
  const float* W3 = (const float*)d_in[5];
  const float* b3 = (const float*)d_in[6];
  float* out = (float*)d_out;

  float* ws = (float*)d_ws;
  float* pooled = ws;                                   // 262144 f
  float* invn   = ws + 262144;                          // 1024 f
  float* ssq    = ws + 263168;                          // 147456 f
  float* scale1 = ws + 410624;                          // 1024 f
  float* shift1 = ws + 411648;                          // 1024 f
  float* scale2 = ws + 412672;                          // 1024 f
  float* shift2 = ws + 413696;                          // 1024 f
  float* stats  = ws + 414720;                          // 4096 f (stats1 | stats2)
  float* stats1 = stats;
  float* stats2 = stats + 2048;
  unsigned short* Mbf  = (unsigned short*)(ws + 418816);   // 262144 us (131072 f)
  unsigned short* W3bf = (unsigned short*)(ws + 549888);   // 20480 us  (10240 f)
  unsigned short* W2bf = (unsigned short*)(ws + 560128);   // 36864 us  (18432 f)
  unsigned short* hpix = (unsigned short*)(ws + 578560);   // 9437184 us (4718592 f)
  unsigned short* xT   = (unsigned short*)(ws + 5297152);  // 37748736 us (18874368 f)
  // total ws: 24171520 floats = 96.7 MB
  unsigned short* hh   = (unsigned short*)d_out;           // conv out bf16 (18.9MB of 37.7MB)
  unsigned short* opre = hpix;                             // reuse (hpix dead after conv)

  k_prep<<<dim3(144), dim3(256), 0, stream>>>(W3, W3bf, W2, W2bf, stats);
  k_pool<<<dim3(BB * CC), dim3(256), 0, stream>>>(x, pooled);
  k_invn<<<dim3(BB), dim3(64), 0, stream>>>(pooled, invn);
  k_M<<<dim3(BB), dim3(256), 0, stream>>>(pooled, invn, W1, Mbf);
  k_trans<<<dim3(144, BB), dim3(256), 0, stream>>>(x, xT, ssq);
  k_gemm1<<<dim3(36, BB), dim3(256), 0, stream>>>(xT, Mbf, ssq, b1, hpix, stats1);
  k_finalize<<<dim3(4), dim3(256), 0, stream>>>(stats1, scale1, shift1);
  k_conv_mfma<<<dim3(24, BB), dim3(256), 0, stream>>>(hpix, scale1, shift1, W2bf, b2, hh);
  k_gemm2<<<dim3(36, BB), dim3(256), 0, stream>>>(xT, hh, W3bf, b3, opre, stats2);
  k_finalize<<<dim3(4), dim3(256), 0, stream>>>(stats2, scale2, shift2);
  k_apply<<<dim3(144, BB), dim3(256), 0, stream>>>(opre, scale2, shift2, out);
}

// Round 4
// 215.900 us; speedup vs baseline: 3.8125x; 1.4239x over previous
//
#include <hip/hip_runtime.h>

#define BB 16
#define CC 256
#define HW 9216   // 96*96

typedef short bf16x8 __attribute__((ext_vector_type(8)));
typedef float f32x4 __attribute__((ext_vector_type(4)));

__device__ __forceinline__ unsigned short f2bf(float f) {
  unsigned u = __float_as_uint(f);
  return (unsigned short)((u + 0x7FFFu + ((u >> 16) & 1u)) >> 16);
}
__device__ __forceinline__ float bf2f(unsigned short h) {
  return __uint_as_float(((unsigned)h) << 16);
}

// ---------------- K1: adaptive avg pool 96x96 -> 8x8 per (b,c) plane ----------------
__global__ __launch_bounds__(256) void k_pool(const float* __restrict__ x,
                                              float* __restrict__ pooled) {
  int bc = blockIdx.x;
  const float* plane = x + (size_t)bc * HW;
  __shared__ float rowwin[96][8];
  for (int idx = threadIdx.x; idx < 96 * 8; idx += 256) {
    int y = idx >> 3, wx = idx & 7;
    const float* r = plane + y * 96 + wx * 12;
    float s = 0.f;
#pragma unroll
    for (int i = 0; i < 12; ++i) s += r[i];
    rowwin[y][wx] = s;
  }
  __syncthreads();
  if (threadIdx.x < 64) {
    int wy = threadIdx.x >> 3, wx = threadIdx.x & 7;
    float s = 0.f;
#pragma unroll
    for (int i = 0; i < 12; ++i) s += rowwin[wy * 12 + i][wx];
    pooled[(size_t)bc * 64 + threadIdx.x] = s * (1.0f / 144.0f);
  }
}

// ---------------- K2: inverse L2 norm over channels of pooled, per (b,p) ----------------
__global__ __launch_bounds__(256) void k_invn(const float* __restrict__ pooled,
                                              float* __restrict__ invn) {
  int b = blockIdx.x;
  int p = threadIdx.x & 63, cg = threadIdx.x >> 6;
  const float* pb = pooled + (size_t)b * CC * 64;
  float s = 0.f;
  for (int c = cg; c < CC; c += 4) { float v = pb[c * 64 + p]; s += v * v; }
  __shared__ float sm[4][64];
  sm[cg][p] = s;
  __syncthreads();
  if (threadIdx.x < 64) {
    float tot = sm[0][p] + sm[1][p] + sm[2][p] + sm[3][p];
    invn[b * 64 + p] = 1.0f / fmaxf(sqrtf(tot), 1e-12f);
  }
}

// ---------------- K3: Mbf[b][o][c] = bf16( sum_p W1[o][p] * ker[b][c][p] ) ----------------
// grid (16 c-groups, 16 b), 256 threads; 4 outputs/thread
__global__ __launch_bounds__(256) void k_M(const float* __restrict__ pooled,
                                           const float* __restrict__ invn,
                                           const float* __restrict__ W1,
                                           unsigned short* __restrict__ Mbf) {
  int c0 = blockIdx.x * 16, b = blockIdx.y, t = threadIdx.x;
  __shared__ float W1s[64][65];
  __shared__ float kers[16][65];
  __shared__ float invs[64];
  if (t < 64) invs[t] = invn[b * 64 + t];
  for (int i = t; i < 4096; i += 256) W1s[i >> 6][i & 63] = W1[i];
  __syncthreads();
  for (int i = t; i < 1024; i += 256) {
    int c = i >> 6, p = i & 63;
    kers[c][p] = pooled[((size_t)b * CC + c0 + c) * 64 + p] * invs[p];
  }
  __syncthreads();
  int c = t & 15, og = t >> 4;
  float s0 = 0.f, s1 = 0.f, s2 = 0.f, s3 = 0.f;
#pragma unroll
  for (int p = 0; p < 64; ++p) {
    float kv = kers[c][p];
    s0 = fmaf(W1s[og * 4 + 0][p], kv, s0);
    s1 = fmaf(W1s[og * 4 + 1][p], kv, s1);
    s2 = fmaf(W1s[og * 4 + 2][p], kv, s2);
    s3 = fmaf(W1s[og * 4 + 3][p], kv, s3);
  }
  unsigned short* Mb = Mbf + (size_t)b * 64 * 256 + c0 + c;
  Mb[(og * 4 + 0) * 256] = f2bf(s0);
  Mb[(og * 4 + 1) * 256] = f2bf(s1);
  Mb[(og * 4 + 2) * 256] = f2bf(s2);
  Mb[(og * 4 + 3) * 256] = f2bf(s3);
}

// ---------------- K4: prep: W3 -> bf16 [o][320], W2 -> bf16 [tap][o][f], zero stats ----------------
__global__ void k_prep(const float* __restrict__ W3, unsigned short* __restrict__ W3bf,
                       const float* __restrict__ W2, unsigned short* __restrict__ W2bf,
                       float* __restrict__ statsbuf) {
  int i = blockIdx.x * 256 + threadIdx.x;
  if (i < 64 * 320) W3bf[i] = f2bf(W3[i]);
  if (i < 9 * 64 * 64) {
    int tap = i >> 12, rem = i & 4095;
    int o = rem >> 6, f = rem & 63;
    W2bf[i] = f2bf(W2[(size_t)(o * 64 + f) * 9 + tap]);
  }
  if (i < 4096) statsbuf[i] = 0.f;
}

// ---------------- K5: transpose x -> xT bf16 [b][pix][256c] + ssq[b][pix] ----------------
__global__ __launch_bounds__(256) void k_trans(const float* __restrict__ x,
                                               unsigned short* __restrict__ xT,
                                               float* __restrict__ ssq) {
  int b = blockIdx.y;
  int px0 = blockIdx.x * 64;
  int t = threadIdx.x;
  int px = t & 63, cg = t >> 6;            // 64 pixels x 4 channel-groups
  __shared__ unsigned char sm[32768];      // [64 px][256 c] bf16, 16B-swizzled
  __shared__ float sq[64];
  if (t < 64) sq[t] = 0.f;
  __syncthreads();
  float part = 0.f;
  const float* xb = x + (size_t)b * CC * HW + px0 + px;
#pragma unroll
  for (int kk = 0; kk < 8; ++kk) {
    int c = cg * 64 + kk * 8;
    float v[8];
#pragma unroll
    for (int j = 0; j < 8; ++j) {
      v[j] = xb[(size_t)(c + j) * HW];
      part += v[j] * v[j];
    }
    uint4 pk;
    pk.x = (unsigned)f2bf(v[0]) | ((unsigned)f2bf(v[1]) << 16);
    pk.y = (unsigned)f2bf(v[2]) | ((unsigned)f2bf(v[3]) << 16);
    pk.z = (unsigned)f2bf(v[4]) | ((unsigned)f2bf(v[5]) << 16);
    pk.w = (unsigned)f2bf(v[6]) | ((unsigned)f2bf(v[7]) << 16);
    int u = cg * 8 + kk;                   // 16B unit within 512B pixel row
    *(uint4*)(sm + px * 512 + ((u ^ (px & 31)) << 4)) = pk;
  }
  atomicAdd(&sq[px], part);
  __syncthreads();
  uint4* dst = (uint4*)(xT + ((size_t)b * HW + px0) * 256);
  for (int i = t; i < 2048; i += 256) {
    int p = i >> 5, q = i & 31;
    dst[i] = *(const uint4*)(sm + p * 512 + ((q ^ (p & 31)) << 4));
  }
  if (t < 64) ssq[(size_t)b * HW + px0 + t] = sq[t];
}

// ---------------- K6: gemm1 MFMA: h = invn*(M·x) + b1 -> hpix bf16 [b][pix][64] + stats ----------------
__global__ __launch_bounds__(256) void k_gemm1(
    const unsigned short* __restrict__ xT,
    const unsigned short* __restrict__ Mbf,
    const float* __restrict__ ssq,
    const float* __restrict__ b1,
    unsigned short* __restrict__ hpix,
    float* __restrict__ stats1) {
  int tile = blockIdx.x, b = blockIdx.y, t = threadIdx.x;
  int w = t >> 6, lane = t & 63, l15 = lane & 15, l4 = lane >> 4;
  int pixbase = tile * 256;
  __shared__ unsigned char Alds[32768];    // A: [64 o][256 c] bf16 swizzled; reused as epi tile
  __shared__ float sb[128];
  {
    const uint4* src = (const uint4*)(Mbf + (size_t)b * 64 * 256);
    for (int i = t; i < 2048; i += 256) {
      int o = i >> 5, u = i & 31;
      *(uint4*)(Alds + o * 512 + ((u ^ (o & 7)) << 4)) = src[i];
    }
  }
  if (t < 128) sb[t] = 0.f;
  __syncthreads();
  f32x4 acc[4][4];
#pragma unroll
  for (int mf = 0; mf < 4; ++mf)
#pragma unroll
    for (int nf = 0; nf < 4; ++nf) { f32x4 z = {0.f,0.f,0.f,0.f}; acc[mf][nf] = z; }
  const unsigned short* xrow = xT + ((size_t)b * HW + pixbase + w * 64) * 256;
#pragma unroll
  for (int kk = 0; kk < 8; ++kk) {
    bf16x8 afr[4], bfr[4];
    int u = kk * 4 + l4;
#pragma unroll
    for (int mf = 0; mf < 4; ++mf)
      afr[mf] = *(const bf16x8*)(Alds + (mf * 16 + l15) * 512 + ((u ^ (l15 & 7)) << 4));
#pragma unroll
    for (int nf = 0; nf < 4; ++nf)
      bfr[nf] = *(const bf16x8*)(xrow + (size_t)(nf * 16 + l15) * 256 + kk * 32 + l4 * 8);
#pragma unroll
    for (int mf = 0; mf < 4; ++mf)
#pragma unroll
      for (int nf = 0; nf < 4; ++nf)
        acc[mf][nf] = __builtin_amdgcn_mfma_f32_16x16x32_bf16(afr[mf], bfr[nf], acc[mf][nf], 0, 0, 0);
  }
  // epilogue
  float invs[4];
  const float* ssqb = ssq + (size_t)b * HW + pixbase + w * 64;
#pragma unroll
  for (int nf = 0; nf < 4; ++nf)
    invs[nf] = 1.0f / fmaxf(sqrtf(ssqb[nf * 16 + l15]), 1e-12f);
  float b1v[4][4];
#pragma unroll
  for (int mf = 0; mf < 4; ++mf)
#pragma unroll
    for (int i = 0; i < 4; ++i) b1v[mf][i] = b1[mf * 16 + l4 * 4 + i];
  float s_acc[4][4], ss_acc[4][4];
#pragma unroll
  for (int mf = 0; mf < 4; ++mf)
#pragma unroll
    for (int i = 0; i < 4; ++i) { s_acc[mf][i] = 0.f; ss_acc[mf][i] = 0.f; }
  __syncthreads();                          // A reads done; reuse Alds as [256px][64o] tile
#pragma unroll
  for (int mf = 0; mf < 4; ++mf)
#pragma unroll
    for (int nf = 0; nf < 4; ++nf) {
      float hv[4];
#pragma unroll
      for (int i = 0; i < 4; ++i) {
        hv[i] = fmaf(acc[mf][nf][i], invs[nf], b1v[mf][i]);
        s_acc[mf][i] += hv[i];
        ss_acc[mf][i] += hv[i] * hv[i];
      }
      uint2 pk;
      pk.x = (unsigned)f2bf(hv[0]) | ((unsigned)f2bf(hv[1]) << 16);
      pk.y = (unsigned)f2bf(hv[2]) | ((unsigned)f2bf(hv[3]) << 16);
      int px = w * 64 + nf * 16 + l15;
      int v = mf * 4 + l4;                  // 8B unit within 128B pixel row
      *(uint2*)(Alds + px * 128 + ((v ^ ((px & 7) << 1)) << 3)) = pk;
    }
#pragma unroll
  for (int mf = 0; mf < 4; ++mf)
#pragma unroll
    for (int i = 0; i < 4; ++i) {
      float s = s_acc[mf][i], q = ss_acc[mf][i];
#pragma unroll
      for (int m = 1; m < 16; m <<= 1) {
        s += __shfl_xor(s, m);
        q += __shfl_xor(q, m);
      }
      if (l15 == 0) {
        int o = mf * 16 + l4 * 4 + i;
        atomicAdd(&sb[o * 2], s);
        atomicAdd(&sb[o * 2 + 1], q);
      }
    }
  __syncthreads();
  uint4* dst = (uint4*)(hpix + ((size_t)b * HW + pixbase) * 64);
  for (int i = t; i < 2048; i += 256) {
    int p = i >> 3, u16 = i & 7;
    dst[i] = *(const uint4*)(Alds + p * 128 + ((u16 ^ (p & 7)) << 4));
  }
  if (t < 64) {
    atomicAdd(&stats1[(b * 64 + t) * 2], sb[t * 2]);
    atomicAdd(&stats1[(b * 64 + t) * 2 + 1], sb[t * 2 + 1]);
  }
}

// ---------------- K8: conv3x3 MFMA -> hh bf16 pixel-major [b][pix][64] (in d_out) ----------------
__global__ __launch_bounds__(256) void k_conv_mfma(
    const unsigned short* __restrict__ hpix,
    const float* __restrict__ stats1,
    const unsigned short* __restrict__ W2bf, const float* __restrict__ b2,
    unsigned short* __restrict__ hh) {
  int band = blockIdx.x;              // 0..23 (4 rows each)
  int b = blockIdx.y;
  int t = threadIdx.x;
  int w = t >> 6;
  int lane = t & 63;
  int l15 = lane & 15, l4 = lane >> 4;

  __shared__ unsigned char smem[49152];  // hs (37.6KB) then reused as epi tile (48KB)
  __shared__ float scs[64], shs[64];
  if (t < 64) {
    float S = stats1[(b * 64 + t) * 2], SS = stats1[(b * 64 + t) * 2 + 1];
    float mean = S * (1.0f / (float)HW);
    float var = SS * (1.0f / (float)HW) - mean * mean;
    float rstd = rsqrtf(var + 1e-5f);
    scs[t] = rstd;
    shs[t] = -mean * rstd;
  }

  f32x4 acc[4][6];
#pragma unroll
  for (int mf = 0; mf < 4; ++mf)
#pragma unroll
    for (int nf = 0; nf < 6; ++nf) { f32x4 z = {0.f,0.f,0.f,0.f}; acc[mf][nf] = z; }

  for (int f0 = 0; f0 < 64; f0 += 32) {
    __syncthreads();
    for (int idx = t; idx < 6 * 98 * 8; idx += 256) {
      int f4 = idx & 7;
      int v = idx >> 3;
      int xr = v % 98;
      int r = v / 98;
      int gy = band * 4 - 1 + r;
      int gx = xr - 1;
      unsigned pk0 = 0, pk1 = 0;
      if ((unsigned)gy < 96u && (unsigned)gx < 96u) {
        const ushort4 rv = *(const ushort4*)(hpix +
            ((size_t)((size_t)b * HW + gy * 96 + gx) * 64 + f0 + f4 * 4));
        int fb = f0 + f4 * 4;
        float v0 = fmaxf(0.f, fmaf(bf2f(rv.x), scs[fb],     shs[fb]));
        float v1 = fmaxf(0.f, fmaf(bf2f(rv.y), scs[fb + 1], shs[fb + 1]));
        float v2 = fmaxf(0.f, fmaf(bf2f(rv.z), scs[fb + 2], shs[fb + 2]));
        float v3 = fmaxf(0.f, fmaf(bf2f(rv.w), scs[fb + 3], shs[fb + 3]));
        pk0 = (unsigned)f2bf(v0) | ((unsigned)f2bf(v1) << 16);
        pk1 = (unsigned)f2bf(v2) | ((unsigned)f2bf(v3) << 16);
      }
      int g = f4 >> 1;
      int gs = g ^ ((xr >> 1) & 3);
      unsigned loff = (unsigned)((r * 98 + xr) * 64 + gs * 16 + (f4 & 1) * 8);
      *(uint2*)(smem + loff) = make_uint2(pk0, pk1);
    }
    __syncthreads();
#pragma unroll
    for (int dy = 0; dy < 3; ++dy) {
      int r = w + dy;
#pragma unroll
      for (int dx = 0; dx < 3; ++dx) {
        int tap = dy * 3 + dx;
        bf16x8 afr[4];
#pragma unroll
        for (int mf = 0; mf < 4; ++mf) {
          int o = mf * 16 + l15;
          afr[mf] = *(const bf16x8*)(W2bf + ((size_t)(tap * 64 + o) * 64 + f0 + l4 * 8));
        }
#pragma unroll
        for (int nf = 0; nf < 6; ++nf) {
          int xr = nf * 16 + l15 + dx;
          unsigned loff = (unsigned)((r * 98 + xr) * 64 + ((l4 ^ ((xr >> 1) & 3)) * 16));
          bf16x8 bfr = *(const bf16x8*)(smem + loff);
#pragma unroll
          for (int mf = 0; mf < 4; ++mf)
            acc[mf][nf] = __builtin_amdgcn_mfma_f32_16x16x32_bf16(
                afr[mf], bfr, acc[mf][nf], 0, 0, 0);
        }
      }
    }
  }
  // epilogue: pack bf16 pixel-major via LDS tile [384 px][64 o]
  float b2v[4][4];
#pragma unroll
  for (int mf = 0; mf < 4; ++mf)
#pragma unroll
    for (int i = 0; i < 4; ++i) b2v[mf][i] = b2[mf * 16 + l4 * 4 + i];
  __syncthreads();
#pragma unroll
  for (int mf = 0; mf < 4; ++mf)
#pragma unroll
    for (int nf = 0; nf < 6; ++nf) {
      int tpx = w * 96 + nf * 16 + l15;
      float h0 = acc[mf][nf][0] + b2v[mf][0];
      float h1 = acc[mf][nf][1] + b2v[mf][1];
      float h2 = acc[mf][nf][2] + b2v[mf][2];
      float h3 = acc[mf][nf][3] + b2v[mf][3];
      uint2 pk;
      pk.x = (unsigned)f2bf(h0) | ((unsigned)f2bf(h1) << 16);
      pk.y = (unsigned)f2bf(h2) | ((unsigned)f2bf(h3) << 16);
      int v = mf * 4 + l4;
      *(uint2*)(smem + tpx * 128 + ((v ^ ((tpx & 7) << 1)) << 3)) = pk;
    }
  __syncthreads();
  uint4* dst = (uint4*)(hh + ((size_t)b * HW + band * 384) * 64);
  for (int i = t; i < 3072; i += 256) {
    int p = i >> 3, u16 = i & 7;
    dst[i] = *(const uint4*)(smem + p * 128 + ((u16 ^ (p & 7)) << 4));
  }
}

// ---------------- K9: gemm2 MFMA: outpre = W3·cat(x,hh) + b3 -> opre bf16 + stats ----------------
__global__ __launch_bounds__(256) void k_gemm2(
    const unsigned short* __restrict__ xT,
    const unsigned short* __restrict__ hh,
    const unsigned short* __restrict__ W3bf,
    const float* __restrict__ b3,
    unsigned short* __restrict__ opre,
    float* __restrict__ stats2) {
  int tile = blockIdx.x, b = blockIdx.y, t = threadIdx.x;
  int w = t >> 6, lane = t & 63, l15 = lane & 15, l4 = lane >> 4;
  int pixbase = tile * 256;
  __shared__ unsigned char Alds[40960];    // A: [64 o][320 c] bf16 swizzled; reused as epi tile
  __shared__ float sb[128];
  {
    const uint4* src = (const uint4*)W3bf;
    for (int i = t; i < 2560; i += 256) {
      int o = i / 40, u = i - o * 40;
      *(uint4*)(Alds + o * 640 + ((u ^ (o & 7)) << 4)) = src[i];
    }
  }
  if (t < 128) sb[t] = 0.f;
  __syncthreads();
  f32x4 acc[4][4];
#pragma unroll
  for (int mf = 0; mf < 4; ++mf)
#pragma unroll
    for (int nf = 0; nf < 4; ++nf) { f32x4 z = {0.f,0.f,0.f,0.f}; acc[mf][nf] = z; }
  const unsigned short* xrow = xT + ((size_t)b * HW + pixbase + w * 64) * 256;
  const unsigned short* hrow = hh + ((size_t)b * HW + pixbase + w * 64) * 64;
#pragma unroll
  for (int kk = 0; kk < 8; ++kk) {
    bf16x8 afr[4], bfr[4];
    int u = kk * 4 + l4;
#pragma unroll
    for (int mf = 0; mf < 4; ++mf)
      afr[mf] = *(const bf16x8*)(Alds + (mf * 16 + l15) * 640 + ((u ^ (l15 & 7)) << 4));
#pragma unroll
    for (int nf = 0; nf < 4; ++nf)
      bfr[nf] = *(const bf16x8*)(xrow + (size_t)(nf * 16 + l15) * 256 + kk * 32 + l4 * 8);
#pragma unroll
    for (int mf = 0; mf < 4; ++mf)
#pragma unroll
      for (int nf = 0; nf < 4; ++nf)
        acc[mf][nf] = __builtin_amdgcn_mfma_f32_16x16x32_bf16(afr[mf], bfr[nf], acc[mf][nf], 0, 0, 0);
  }
#pragma unroll
  for (int kk = 8; kk < 10; ++kk) {
    bf16x8 afr[4], bfr[4];
    int u = kk * 4 + l4;
#pragma unroll
    for (int mf = 0; mf < 4; ++mf)
      afr[mf] = *(const bf16x8*)(Alds + (mf * 16 + l15) * 640 + ((u ^ (l15 & 7)) << 4));
#pragma unroll
    for (int nf = 0; nf < 4; ++nf)
      bfr[nf] = *(const bf16x8*)(hrow + (size_t)(nf * 16 + l15) * 64 + (kk - 8) * 32 + l4 * 8);
#pragma unroll
    for (int mf = 0; mf < 4; ++mf)
#pragma unroll
      for (int nf = 0; nf < 4; ++nf)
        acc[mf][nf] = __builtin_amdgcn_mfma_f32_16x16x32_bf16(afr[mf], bfr[nf], acc[mf][nf], 0, 0, 0);
  }
  float b3v[4][4];
#pragma unroll
  for (int mf = 0; mf < 4; ++mf)
#pragma unroll
    for (int i = 0; i < 4; ++i) b3v[mf][i] = b3[mf * 16 + l4 * 4 + i];
  float s_acc[4][4], ss_acc[4][4];
#pragma unroll
  for (int mf = 0; mf < 4; ++mf)
#pragma unroll
    for (int i = 0; i < 4; ++i) { s_acc[mf][i] = 0.f; ss_acc[mf][i] = 0.f; }
  __syncthreads();
#pragma unroll
  for (int mf = 0; mf < 4; ++mf)
#pragma unroll
    for (int nf = 0; nf < 4; ++nf) {
      float hv[4];
#pragma unroll
      for (int i = 0; i < 4; ++i) {
        hv[i] = acc[mf][nf][i] + b3v[mf][i];
        s_acc[mf][i] += hv[i];
        ss_acc[mf][i] += hv[i] * hv[i];
      }
      uint2 pk;
      pk.x = (unsigned)f2bf(hv[0]) | ((unsigned)f2bf(hv[1]) << 16);
      pk.y = (unsigned)f2bf(hv[2]) | ((unsigned)f2bf(hv[3]) << 16);
      int px = w * 64 + nf * 16 + l15;
      int v = mf * 4 + l4;
      *(uint2*)(Alds + px * 128 + ((v ^ ((px & 7) << 1)) << 3)) = pk;
    }
#pragma unroll
  for (int mf = 0; mf < 4; ++mf)
#pragma unroll
    for (int i = 0; i < 4; ++i) {
      float s = s_acc[mf][i], q = ss_acc[mf][i];
#pragma unroll
      for (int m = 1; m < 16; m <<= 1) {
        s += __shfl_xor(s, m);
        q += __shfl_xor(q, m);
      }
      if (l15 == 0) {
        int o = mf * 16 + l4 * 4 + i;
        atomicAdd(&sb[o * 2], s);
        atomicAdd(&sb[o * 2 + 1], q);
      }
    }
  __syncthreads();
  uint4* dst = (uint4*)(opre + ((size_t)b * HW + pixbase) * 64);
  for (int i = t; i < 2048; i += 256) {
    int p = i >> 3, u16 = i & 7;
    dst[i] = *(const uint4*)(Alds + p * 128 + ((u16 ^ (p & 7)) << 4));
  }
  if (t < 64) {
    atomicAdd(&stats2[(b * 64 + t) * 2], sb[t * 2]);
    atomicAdd(&stats2[(b * 64 + t) * 2 + 1], sb[t * 2 + 1]);
  }
}

// ---------------- K10: apply IN+ReLU, transpose to o-major fp32 d_out ----------------
__global__ __launch_bounds__(256) void k_apply(const unsigned short* __restrict__ opre,
                                               const float* __restrict__ stats2,
                                               float* __restrict__ out) {
  int b = blockIdx.y, px0 = blockIdx.x * 64, t = threadIdx.x;
  __shared__ float tile[64][68];
  __shared__ float scs[64], shs[64];
  if (t < 64) {
    float S = stats2[(b * 64 + t) * 2], SS = stats2[(b * 64 + t) * 2 + 1];
    float mean = S * (1.0f / (float)HW);
    float var = SS * (1.0f / (float)HW) - mean * mean;
    float rstd = rsqrtf(var + 1e-5f);
    scs[t] = rstd;
    shs[t] = -mean * rstd;
  }
  __syncthreads();
  const unsigned* src = (const unsigned*)(opre + ((size_t)b * HW + px0) * 64);
  for (int i = t; i < 2048; i += 256) {
    int px = i >> 5, q = i & 31;
    unsigned v = src[i];
    int o = q * 2;
    float f0 = bf2f((unsigned short)(v & 0xffff));
    float f1 = bf2f((unsigned short)(v >> 16));
    tile[o][px]     = fmaxf(0.f, fmaf(f0, scs[o], shs[o]));
    tile[o + 1][px] = fmaxf(0.f, fmaf(f1, scs[o + 1], shs[o + 1]));
  }
  __syncthreads();
  for (int j = t; j < 1024; j += 256) {
    int o = j >> 4, w4 = j & 15;
    float4 v = *(const float4*)(&tile[o][w4 * 4]);
    *(float4*)(out + ((size_t)(b * 64) + o) * HW + px0 + w4 * 4) = v;
  }
}

extern "C" void kernel_launch(void* const* d_in, const int* in_sizes, int n_in,
                              void* d_out, int out_size, void* d_ws, size_t ws_size,
                              hipStream_t stream) {
  const float* x  = (const float*)d_in[0];
  const float* W1 = (const float*)d_in[1];
  const float* b1 = (const float*)d_in[2];
  const float* W2 = (const float*)d_in[3];
  const float* b2 = (const float*)d_in[4];
  const float* W3 = (const float*)d_in[5];
  const float* b3 = (const float*)d_in[6];
  float* out = (float*)d_out;

  float* ws = (float*)d_ws;
  float* pooled = ws;                                   // 262144 f
  float* invn   = ws + 262144;                          // 1024 f
  float* ssq    = ws + 263168;                          // 147456 f
  float* stats  = ws + 414720;                          // 4096 f (stats1 | stats2)
  float* stats1 = stats;
  float* stats2 = stats + 2048;
  unsigned short* Mbf  = (unsigned short*)(ws + 418816);   // 262144 us
  unsigned short* W3bf = (unsigned short*)(ws + 549888);   // 20480 us
  unsigned short* W2bf = (unsigned short*)(ws + 560128);   // 36864 us
  unsigned short* hpix = (unsigned short*)(ws + 578560);   // 9437184 us
  unsigned short* xT   = (unsigned short*)(ws + 5297152);  // 37748736 us
  unsigned short* hh   = (unsigned short*)d_out;           // conv out bf16
  unsigned short* opre = hpix;                             // reuse (hpix dead after conv)

  k_prep<<<dim3(144), dim3(256), 0, stream>>>(W3, W3bf, W2, W2bf, stats);
  k_pool<<<dim3(BB * CC), dim3(256), 0, stream>>>(x, pooled);
  k_invn<<<dim3(BB), dim3(256), 0, stream>>>(pooled, invn);
  k_M<<<dim3(16, BB), dim3(256), 0, stream>>>(pooled, invn, W1, Mbf);
  k_trans<<<dim3(144, BB), dim3(256), 0, stream>>>(x, xT, ssq);
  k_gemm1<<<dim3(36, BB), dim3(256), 0, stream>>>(xT, Mbf, ssq, b1, hpix, stats1);
  k_conv_mfma<<<dim3(24, BB), dim3(256), 0, stream>>>(hpix, stats1, W2bf, b2, hh);
  k_gemm2<<<dim3(36, BB), dim3(256), 0, stream>>>(xT, hh, W3bf, b3, opre, stats2);
  k_apply<<<dim3(144, BB), dim3(256), 0, stream>>>(opre, stats2, out);
}